// Round 4
// baseline (255.852 us; speedup 1.0000x reference)
//
#include <hip/hip_runtime.h>
#include <hip/hip_bf16.h>

typedef __bf16 bf16x8 __attribute__((ext_vector_type(8)));
typedef __bf16 bf16x4 __attribute__((ext_vector_type(4)));
typedef float floatx4 __attribute__((ext_vector_type(4)));

#define AS1 __attribute__((address_space(1)))
#define AS3 __attribute__((address_space(3)))

#define CHUNK_B 32768   // 64 GEMM rows x 512 B fp32
#define WPITCH  272     // W bf16 row pitch (136 elems) -> 2-way-max bank rotation

// y[b,i] (256x128) = x[b,i] (256x128) @ W_i^T + bias_i.
// Grid 256 = 8 channels x 32 j; block 512 thr / 8 waves, 1 block/CU, no tail.
// Block covers b in {4j..4j+3} = 16 chunks of 64 rows.
// W_i: LDS-staged once -> hoisted to 64 VGPR/wave (wave owns 4 out-col tiles),
// LDS region then overlaid by the X ring (4 x 32 KB, staged 3 chunks ahead,
// counted vmcnt never 0, ONE s_barrier per chunk). Plain stores (L2 merge).
__global__ __launch_bounds__(512, 2)
void mcsl_kernel(const float* __restrict__ x,
                 const float* __restrict__ W,
                 const float* __restrict__ bias,
                 float* __restrict__ y)
{
    __shared__ __align__(16) unsigned char LDS[4 * CHUNK_B];  // 128 KiB

    const int tid  = threadIdx.x;
    const int i    = blockIdx.x & 7;
    const int j    = blockIdx.x >> 3;        // 0..31
    const int lane = tid & 63;
    const int wv   = tid >> 6;               // 0..7
    const int nrow = lane & 15;
    const int quad = lane >> 4;

    // ---- stage W_i (fp32 -> bf16, 272 B pitch) into LDS overlay ----
    {
        const float4* Wsrc = (const float4*)(W + (size_t)i * (128 * 128));
        #pragma unroll
        for (int it = 0; it < 8; ++it) {
            int idx = tid + it * 512;          // 4096 float4 total
            float4 w4 = Wsrc[idx];
            int o  = idx >> 5;                 // out-feature row
            int kb = (idx & 31) * 8;           // byte in row
            bf16x4 wq;
            wq[0] = (__bf16)w4.x; wq[1] = (__bf16)w4.y;
            wq[2] = (__bf16)w4.z; wq[3] = (__bf16)w4.w;
            *(bf16x4*)&LDS[o * WPITCH + kb] = wq;
        }
    }

    // bias -> registers (lane owns outcols (ctb+ct)*16 + quad*4 ..+3)
    const int ctb = (wv & 1) * 4;
    floatx4 accB0 = *(const floatx4*)(bias + i * 128 + (ctb + 0) * 16 + quad * 4);
    floatx4 accB1 = *(const floatx4*)(bias + i * 128 + (ctb + 1) * 16 + quad * 4);
    floatx4 accB2 = *(const floatx4*)(bias + i * 128 + (ctb + 2) * 16 + quad * 4);
    floatx4 accB3 = *(const floatx4*)(bias + i * 128 + (ctb + 3) * 16 + quad * 4);
    __syncthreads();   // W writes visible

    // ---- hoist W frags to registers: wf[ct][ks] = W[(ctb+ct)*16+nrow][ks*32+quad*8..+7]
    bf16x8 wf[4][4];
    #pragma unroll
    for (int ct = 0; ct < 4; ++ct)
        #pragma unroll
        for (int ks = 0; ks < 4; ++ks)
            wf[ct][ks] = *(const bf16x8*)&LDS[((ctb + ct) * 16 + nrow) * WPITCH + ks * 64 + quad * 16];
    __syncthreads();   // all hoists retired; X ring may now overwrite the overlay

    // ---- geometry ----
    const int rloc = (wv >> 1) * 16 + nrow;   // row within 64-row chunk
    const int xrow = rloc * 512;
    const int rsw  = (rloc & 7) << 4;
    const size_t base0 = ((size_t)(4 * j) * 8 + i) * 32768;   // floats
    // chunk c: float offset base0 + (c>>2)*262144 + (c&3)*8192

    // ---- STAGE(c): 32 KB chunk -> ring slot c&3. 1 KB contiguous per
    // wave-instruction; inverse row-XOR swizzle baked into the SOURCE address.
#define STAGE(c) do {                                                            \
        const unsigned char* gb = (const unsigned char*)                         \
            (x + base0 + (size_t)((c) >> 2) * 262144 + ((c) & 3) * 8192);        \
        unsigned char* db = (unsigned char*)LDS + ((c) & 3) * CHUNK_B;           \
        _Pragma("unroll")                                                        \
        for (int jj = 0; jj < 4; ++jj) {                                         \
            const int Lu = jj * 8192 + wv * 1024;   /* wave-uniform byte */      \
            const int L  = Lu + lane * 16;                                       \
            const int rr = L >> 9;                                               \
            const int sb = (L & 511) ^ ((rr & 7) << 4);                          \
            __builtin_amdgcn_global_load_lds(                                    \
                (AS1 void*)(gb + (size_t)rr * 512 + sb),                         \
                (AS3 void*)(db + Lu), 16, 0, 0);                                 \
        }                                                                        \
    } while (0)

#define COMPUTE(c) do {                                                          \
        const unsigned char* bb = (const unsigned char*)LDS + ((c) & 3) * CHUNK_B; \
        floatx4 acc0 = accB0, acc1 = accB1, acc2 = accB2, acc3 = accB3;          \
        _Pragma("unroll")                                                        \
        for (int ks = 0; ks < 4; ++ks) {                                         \
            const int kb = ks * 128 + quad * 32;                                 \
            floatx4 xa = *(const floatx4*)(bb + xrow + ((kb)      ^ rsw));       \
            floatx4 xb = *(const floatx4*)(bb + xrow + ((kb + 16) ^ rsw));       \
            bf16x8 xf;                                                           \
            xf[0] = (__bf16)xa.x; xf[1] = (__bf16)xa.y;                          \
            xf[2] = (__bf16)xa.z; xf[3] = (__bf16)xa.w;                          \
            xf[4] = (__bf16)xb.x; xf[5] = (__bf16)xb.y;                          \
            xf[6] = (__bf16)xb.z; xf[7] = (__bf16)xb.w;                          \
            acc0 = __builtin_amdgcn_mfma_f32_16x16x32_bf16(wf[0][ks], xf, acc0, 0, 0, 0); \
            acc1 = __builtin_amdgcn_mfma_f32_16x16x32_bf16(wf[1][ks], xf, acc1, 0, 0, 0); \
            acc2 = __builtin_amdgcn_mfma_f32_16x16x32_bf16(wf[2][ks], xf, acc2, 0, 0, 0); \
            acc3 = __builtin_amdgcn_mfma_f32_16x16x32_bf16(wf[3][ks], xf, acc3, 0, 0, 0); \
        }                                                                        \
        float* yr = y + base0 + (size_t)((c) >> 2) * 262144 + ((c) & 3) * 8192   \
                  + (size_t)rloc * 128 + ctb * 16 + quad * 4;                    \
        *(floatx4*)(yr)      = acc0;                                             \
        *(floatx4*)(yr + 16) = acc1;                                             \
        *(floatx4*)(yr + 32) = acc2;                                             \
        *(floatx4*)(yr + 48) = acc3;                                             \
    } while (0)

    // TAIL(c): issue stage c+3 (slot safe since TAIL(c-1)'s barrier), counted
    // vmcnt drains exactly through chunk c+1's loads, then ONE barrier.
#define TAIL(c, DOSTAGE, LIT) do {                                               \
        if (DOSTAGE) STAGE((c) + 3);                                             \
        asm volatile("s_waitcnt vmcnt(" LIT ")" ::: "memory");                   \
        __builtin_amdgcn_sched_barrier(0);                                       \
        __builtin_amdgcn_s_barrier();                                            \
    } while (0)

    // ---- prologue: 3 chunks in flight; drain chunk 0 only ----
    STAGE(0); STAGE(1); STAGE(2);
    asm volatile("s_waitcnt vmcnt(8)" ::: "memory");
    __builtin_amdgcn_sched_barrier(0);
    __builtin_amdgcn_s_barrier();

    COMPUTE(0);  TAIL(0,  1, "12");
    COMPUTE(1);  TAIL(1,  1, "16");
    COMPUTE(2);  TAIL(2,  1, "16");
    COMPUTE(3);  TAIL(3,  1, "16");
    COMPUTE(4);  TAIL(4,  1, "16");
    COMPUTE(5);  TAIL(5,  1, "16");
    COMPUTE(6);  TAIL(6,  1, "16");
    COMPUTE(7);  TAIL(7,  1, "16");
    COMPUTE(8);  TAIL(8,  1, "16");
    COMPUTE(9);  TAIL(9,  1, "16");
    COMPUTE(10); TAIL(10, 1, "16");
    COMPUTE(11); TAIL(11, 1, "16");
    COMPUTE(12); TAIL(12, 1, "16");   // stages chunk 15 (last)
    COMPUTE(13); TAIL(13, 0, "12");
    COMPUTE(14); TAIL(14, 0, "8");
    COMPUTE(15);

#undef STAGE
#undef COMPUTE
#undef TAIL
}

extern "C" void kernel_launch(void* const* d_in, const int* in_sizes, int n_in,
                              void* d_out, int out_size, void* d_ws, size_t ws_size,
                              hipStream_t stream) {
    const float* x = (const float*)d_in[0];
    const float* W = (const float*)d_in[1];
    const float* b = (const float*)d_in[2];
    float* y = (float*)d_out;
    dim3 grid(256), block(512);
    hipLaunchKernelGGL(mcsl_kernel, grid, block, 0, stream, x, W, b, y);
}

// Round 6
// 245.705 us; speedup vs baseline: 1.0413x; 1.0413x over previous
//
#include <hip/hip_runtime.h>
#include <hip/hip_bf16.h>

typedef __bf16 bf16x8 __attribute__((ext_vector_type(8)));
typedef __bf16 bf16x4 __attribute__((ext_vector_type(4)));
typedef float floatx4 __attribute__((ext_vector_type(4)));

#define WPITCH 272   // bytes; 17*16 -> 16B-aligned rows + bank rotation

// y[b,i] (256x128) = x[b,i] (256x128) @ W_i^T + bias_i
// COPY-SHAPED GEMM: grid 1024 = 8 ch x 128 j; block 256 thr / 4 waves;
// LDS = W(bf16) + bias only (35 KB) -> 4 blocks/CU = 16 waves/CU.
// Wave processes one 16-row tile (8 KB) per round, 4 rounds; the
// (4r+wv, j) -> (b, subtile) map makes all 1024 blocks sweep a dense
// 32 MB window per round (copy-like instantaneous footprint).
// Plain register loads in fragment layout, 1-round-ahead prefetch,
// W frags read from LDS per use, no main-loop barriers.
__global__ __launch_bounds__(256, 4)
void mcsl_kernel(const float* __restrict__ x,
                 const float* __restrict__ W,
                 const float* __restrict__ bias,
                 float* __restrict__ y)
{
    __shared__ __align__(16) unsigned char Wl[128 * WPITCH];  // 34816 B
    __shared__ __align__(16) float blds[128];

    const int tid  = threadIdx.x;
    const int i    = blockIdx.x & 7;     // channel (XCD-pinned W_i)
    const int j    = blockIdx.x >> 3;    // 0..127
    const int lane = tid & 63;
    const int wv   = tid >> 6;           // 0..3
    const int nrow = lane & 15;
    const int quad = lane >> 4;

    // ---- stage W_i (fp32 -> bf16, 272 B pitch) ----
    {
        const float4* Wsrc = (const float4*)(W + (size_t)i * 16384);
        #pragma unroll
        for (int it = 0; it < 16; ++it) {
            int idx = tid + it * 256;          // 4096 float4 total
            float4 w4 = Wsrc[idx];
            int o  = idx >> 5;                 // out-feature row
            int kb = (idx & 31) * 8;           // byte in row
            bf16x4 wq;
            wq[0] = (__bf16)w4.x; wq[1] = (__bf16)w4.y;
            wq[2] = (__bf16)w4.z; wq[3] = (__bf16)w4.w;
            *(bf16x4*)&Wl[o * WPITCH + kb] = wq;
        }
        if (tid < 128) blds[tid] = bias[i * 128 + tid];
    }
    __syncthreads();

    const int jh = j >> 4;      // 0..7: batch sub-index
    const int s  = j & 15;      // 0..15: 16-row subtile within (b,i) region
    // tile (r, wv): b = (4r+wv)*8 + jh; floats base = (b*8 + i)*32768 + s*2048
    // lane load: row nrow (128 floats), k = ks*32 + quad*8 .. +7

    float4 pf[8];
    {
        const int b0 = wv * 8 + jh;
        const float4* sp = (const float4*)(x + ((size_t)(b0 * 8 + i) * 32768
                                                + s * 2048))
                         + nrow * 32 + quad * 2;
        #pragma unroll
        for (int ks = 0; ks < 4; ++ks) {
            pf[2 * ks]     = sp[ks * 8];
            pf[2 * ks + 1] = sp[ks * 8 + 1];
        }
    }

    #pragma unroll
    for (int r = 0; r < 4; ++r) {
        const int b = (4 * r + wv) * 8 + jh;

        // convert current tile to B-fragments (waits on pf loads)
        bf16x8 xf[4];
        #pragma unroll
        for (int ks = 0; ks < 4; ++ks) {
            float4 a0 = pf[2 * ks], a1 = pf[2 * ks + 1];
            bf16x8 v;
            v[0] = (__bf16)a0.x; v[1] = (__bf16)a0.y;
            v[2] = (__bf16)a0.z; v[3] = (__bf16)a0.w;
            v[4] = (__bf16)a1.x; v[5] = (__bf16)a1.y;
            v[6] = (__bf16)a1.z; v[7] = (__bf16)a1.w;
            xf[ks] = v;
        }

        // issue next round's tile loads (hidden under LDS reads + MFMA below)
        if (r < 3) {
            const int bn = (4 * (r + 1) + wv) * 8 + jh;
            const float4* sp = (const float4*)(x + ((size_t)(bn * 8 + i) * 32768
                                                    + s * 2048))
                             + nrow * 32 + quad * 2;
            #pragma unroll
            for (int ks = 0; ks < 4; ++ks) {
                pf[2 * ks]     = sp[ks * 8];
                pf[2 * ks + 1] = sp[ks * 8 + 1];
            }
        }

        // acc init = bias; lane owns out-cols ct*16 + quad*4 .. +3 at x-row nrow
        floatx4 acc[8];
        #pragma unroll
        for (int ct = 0; ct < 8; ++ct)
            acc[ct] = *(const floatx4*)&blds[ct * 16 + quad * 4];

        #pragma unroll
        for (int ks = 0; ks < 4; ++ks) {
            #pragma unroll
            for (int ct = 0; ct < 8; ++ct) {
                bf16x8 wf = *(const bf16x8*)&Wl[(ct * 16 + nrow) * WPITCH
                                                + ks * 64 + quad * 16];
                acc[ct] = __builtin_amdgcn_mfma_f32_16x16x32_bf16(
                              wf, xf[ks], acc[ct], 0, 0, 0);
            }
        }

        float* yr = y + ((size_t)(b * 8 + i) * 32768 + s * 2048)
                  + nrow * 128 + quad * 4;
        #pragma unroll
        for (int ct = 0; ct < 8; ++ct)
            *(floatx4*)(yr + ct * 16) = acc[ct];
    }
}

extern "C" void kernel_launch(void* const* d_in, const int* in_sizes, int n_in,
                              void* d_out, int out_size, void* d_ws, size_t ws_size,
                              hipStream_t stream) {
    const float* x = (const float*)d_in[0];
    const float* W = (const float*)d_in[1];
    const float* b = (const float*)d_in[2];
    float* y = (float*)d_out;
    dim3 grid(1024), block(256);
    hipLaunchKernelGGL(mcsl_kernel, grid, block, 0, stream, x, W, b, y);
}

// Round 7
// 240.837 us; speedup vs baseline: 1.0623x; 1.0202x over previous
//
#include <hip/hip_runtime.h>
#include <hip/hip_bf16.h>

typedef __bf16 bf16x8 __attribute__((ext_vector_type(8)));
typedef __bf16 bf16x4 __attribute__((ext_vector_type(4)));
typedef float floatx4 __attribute__((ext_vector_type(4)));

#define WPITCH 272   // bytes; 17*16 -> 16B-aligned rows + bank rotation

// y[b,i] (256x128) = x[b,i] (256x128) @ W_i^T + bias_i
// Round-6 structure (verified) + CONTIGUOUS STORE PATH:
// wave's 16x128 output tile (= contiguous 8 KB of y) is staged in a
// wave-private XOR-swizzled LDS buffer, then written as 8 x 1KB-contiguous
// nontemporal stores (full 128B lines, no write-allocate -> no L3 x-eviction).
// Grid 1024 = 8 ch x 128 j; block 256 thr / 4 waves; LDS 68 KB -> 2 blocks/CU.
__global__ __launch_bounds__(256, 2)
void mcsl_kernel(const float* __restrict__ x,
                 const float* __restrict__ W,
                 const float* __restrict__ bias,
                 float* __restrict__ y)
{
    __shared__ __align__(16) unsigned char Wl[128 * WPITCH];  // 34816 B
    __shared__ __align__(16) float blds[128];
    __shared__ __align__(16) unsigned char Obuf[4][8192];     // per-wave out tile

    const int tid  = threadIdx.x;
    const int i    = blockIdx.x & 7;     // channel (XCD-pinned W_i)
    const int j    = blockIdx.x >> 3;    // 0..127
    const int lane = tid & 63;
    const int wv   = tid >> 6;           // 0..3
    const int nrow = lane & 15;
    const int quad = lane >> 4;

    // ---- stage W_i (fp32 -> bf16, 272 B pitch) ----
    {
        const float4* Wsrc = (const float4*)(W + (size_t)i * 16384);
        #pragma unroll
        for (int it = 0; it < 16; ++it) {
            int idx = tid + it * 256;          // 4096 float4 total
            float4 w4 = Wsrc[idx];
            int o  = idx >> 5;                 // out-feature row
            int kb = (idx & 31) * 8;           // byte in row
            bf16x4 wq;
            wq[0] = (__bf16)w4.x; wq[1] = (__bf16)w4.y;
            wq[2] = (__bf16)w4.z; wq[3] = (__bf16)w4.w;
            *(bf16x4*)&Wl[o * WPITCH + kb] = wq;
        }
        if (tid < 128) blds[tid] = bias[i * 128 + tid];
    }
    __syncthreads();

    const int jh = j >> 4;      // 0..7: batch sub-index
    const int s  = j & 15;      // 0..15: 16-row subtile within (b,i) region
    unsigned char* ob = Obuf[wv];

    float4 pf[8];
    {
        const int b0 = wv * 8 + jh;
        const float4* sp = (const float4*)(x + ((size_t)(b0 * 8 + i) * 32768
                                                + s * 2048))
                         + nrow * 32 + quad * 2;
        #pragma unroll
        for (int ks = 0; ks < 4; ++ks) {
            pf[2 * ks]     = sp[ks * 8];
            pf[2 * ks + 1] = sp[ks * 8 + 1];
        }
    }

    #pragma unroll
    for (int r = 0; r < 4; ++r) {
        const int b = (4 * r + wv) * 8 + jh;

        // convert current tile to B-fragments (waits on pf loads)
        bf16x8 xf[4];
        #pragma unroll
        for (int ks = 0; ks < 4; ++ks) {
            float4 a0 = pf[2 * ks], a1 = pf[2 * ks + 1];
            bf16x8 v;
            v[0] = (__bf16)a0.x; v[1] = (__bf16)a0.y;
            v[2] = (__bf16)a0.z; v[3] = (__bf16)a0.w;
            v[4] = (__bf16)a1.x; v[5] = (__bf16)a1.y;
            v[6] = (__bf16)a1.z; v[7] = (__bf16)a1.w;
            xf[ks] = v;
        }

        // issue next round's tile loads (hidden under LDS reads + MFMA below)
        if (r < 3) {
            const int bn = (4 * (r + 1) + wv) * 8 + jh;
            const float4* sp = (const float4*)(x + ((size_t)(bn * 8 + i) * 32768
                                                    + s * 2048))
                             + nrow * 32 + quad * 2;
            #pragma unroll
            for (int ks = 0; ks < 4; ++ks) {
                pf[2 * ks]     = sp[ks * 8];
                pf[2 * ks + 1] = sp[ks * 8 + 1];
            }
        }

        // acc init = bias; lane owns out-cols ct*16 + quad*4 .. +3 at x-row nrow
        floatx4 acc[8];
        #pragma unroll
        for (int ct = 0; ct < 8; ++ct)
            acc[ct] = *(const floatx4*)&blds[ct * 16 + quad * 4];

        #pragma unroll
        for (int ks = 0; ks < 4; ++ks) {
            #pragma unroll
            for (int ct = 0; ct < 8; ++ct) {
                bf16x8 wf = *(const bf16x8*)&Wl[(ct * 16 + nrow) * WPITCH
                                                + ks * 64 + quad * 16];
                acc[ct] = __builtin_amdgcn_mfma_f32_16x16x32_bf16(
                              wf, xf[ks], acc[ct], 0, 0, 0);
            }
        }

        // ---- stage out tile in wave-private LDS (XOR-swizzled rows) ----
        // logical (row=nrow, colbyte=ct*64+quad*16); slot col = colbyte ^ ((row&7)<<4)
        #pragma unroll
        for (int ct = 0; ct < 8; ++ct) {
            const int cb = ct * 64 + quad * 16;
            *(floatx4*)&ob[nrow * 512 + (cb ^ ((nrow & 7) << 4))] = acc[ct];
        }
        asm volatile("s_waitcnt lgkmcnt(0)" ::: "memory");
        __builtin_amdgcn_sched_barrier(0);

        // ---- drain: 8 x 1KB-contiguous nontemporal stores (full lines) ----
        unsigned char* yt = (unsigned char*)(y + ((size_t)(b * 8 + i) * 32768
                                                  + s * 2048));
        #pragma unroll
        for (int p = 0; p < 8; ++p) {
            const int o  = p * 1024 + lane * 16;
            const int rr = o >> 9;
            floatx4 v = *(const floatx4*)&ob[rr * 512
                                             + ((o & 511) ^ ((rr & 7) << 4))];
            __builtin_nontemporal_store(v, (floatx4*)(yt + o));
        }
    }
}

extern "C" void kernel_launch(void* const* d_in, const int* in_sizes, int n_in,
                              void* d_out, int out_size, void* d_ws, size_t ws_size,
                              hipStream_t stream) {
    const float* x = (const float*)d_in[0];
    const float* W = (const float*)d_in[1];
    const float* b = (const float*)d_in[2];
    float* y = (float*)d_out;
    dim3 grid(1024), block(256);
    hipLaunchKernelGGL(mcsl_kernel, grid, block, 0, stream, x, W, b, y);
}